// Round 6
// baseline (983.733 us; speedup 1.0000x reference)
//
#include <hip/hip_runtime.h>

// PureWaveAttention: B=2,T=2048,D=1024,H=16,NW=64,HD=64 — ALL FP32 I/O.
// Pipeline:
//  1) proj_wave4: ALL FOUR projections (qf,qp,kf,kp) in one block per
//     (128-t-tile, h): shared x-tile, 512 FMA per 24 LDS reads per kk-step.
//     Epilogue: sin(f*t+p), L2-normalize -> qn, kn  fp32 [B,T,H,64]
//  2) gemm: v = x@Wv+bv   (128x128 tile, BK=32, 8x8, sw-pipelined)
//  3) CHUNKED LINEAR ATTENTION:
//     a) chunk_kv:  G_c = K_c^T V_c
//     b) prefix:    M_c = sum_{c'<c} G_c'  (in-place exclusive prefix)
//     c) attn_chunk: O_c = (Q_c M_c + tril(Q_c K_c^T) V_c) * scale/sqrt(t+1)
//  4) gemm: d_out = att@Wo+bo
// ws (64 MB): qn | kn | vbuf | G. att ALIASES qn (block (c,h) is sole reader
// of its qn slab and loads it to LDS before overwriting with att).
// NUMERICS: fp32 end-to-end (threshold 1.5e-2 abs, |ref|~450; phase f*t+p
// amplifies f-error by t<=2047 -> no bf16/MFMA anywhere).

#define Bb 2
#define Tt 2048
#define Dd 1024
#define Hh 16
#define NC 32   // T/64 chunks

// ---------------------------------------------------------------------------
// Kernel 1: fused q+k, f+p projection + sin + L2-normalize.
// Tile 128(t) x 64(head cols) x 4 matrices. BK=32. Per thread: 8 rows x
// 4 cols x 4 mats = 128 acc. Global->reg prefetch overlaps compute.
// ---------------------------------------------------------------------------
__global__ __launch_bounds__(256, 2) void proj_wave4_kernel(
    const float* __restrict__ X,
    const float* __restrict__ Wqf, const float* __restrict__ bqf,
    const float* __restrict__ Wqp, const float* __restrict__ bqp,
    const float* __restrict__ Wkf, const float* __restrict__ bkf,
    const float* __restrict__ Wkp, const float* __restrict__ bkp,
    float* __restrict__ QN, float* __restrict__ KN)
{
  __shared__ float As[128][36];      // 18.0 KB
  __shared__ float Ws[4][32][68];    // 34.0 KB  (qf,qp,kf,kp)

  const int tid = threadIdx.x;
  const int ty = tid >> 4, tx = tid & 15;
  const int mb = blockIdx.x, h = blockIdx.y, b = blockIdx.z;
  const int row0 = b * Tt + mb * 128;
  const int col0 = h * 64;
  const float* Wm[4] = {Wqf, Wqp, Wkf, Wkp};

  float acc[4][8][4] = {{{0.f}}};    // [mat][row][col]

  // staging offsets
  const int ar = tid >> 3, ac4 = (tid & 7) * 4;        // +j*32 rows
  const int wkr = tid >> 4, wc4 = (tid & 15) * 4;      // +j*16 rows

  float4 ra[4], rw[4][2];
  // prefetch iter 0
  {
    #pragma unroll
    for (int j = 0; j < 4; ++j)
      ra[j] = *(const float4*)&X[(size_t)(row0 + ar + j * 32) * Dd + ac4];
    #pragma unroll
    for (int m = 0; m < 4; ++m)
      #pragma unroll
      for (int j = 0; j < 2; ++j)
        rw[m][j] = *(const float4*)&Wm[m][(size_t)(wkr + j * 16) * Dd + col0 + wc4];
  }

  for (int k0 = 0; k0 < Dd; k0 += 32) {
    #pragma unroll
    for (int j = 0; j < 4; ++j)
      *(float4*)&As[ar + j * 32][ac4] = ra[j];
    #pragma unroll
    for (int m = 0; m < 4; ++m)
      #pragma unroll
      for (int j = 0; j < 2; ++j)
        *(float4*)&Ws[m][wkr + j * 16][wc4] = rw[m][j];
    __syncthreads();

    if (k0 + 32 < Dd) {  // prefetch next k-slab (overlaps compute below)
      const int kn0 = k0 + 32;
      #pragma unroll
      for (int j = 0; j < 4; ++j)
        ra[j] = *(const float4*)&X[(size_t)(row0 + ar + j * 32) * Dd + kn0 + ac4];
      #pragma unroll
      for (int m = 0; m < 4; ++m)
        #pragma unroll
        for (int j = 0; j < 2; ++j)
          rw[m][j] = *(const float4*)&Wm[m][(size_t)(kn0 + wkr + j * 16) * Dd + col0 + wc4];
    }

    #pragma unroll
    for (int kk = 0; kk < 32; kk += 4) {
      float4 a4[8];
      #pragma unroll
      for (int i = 0; i < 4; ++i) {
        a4[i]     = *(const float4*)&As[ty * 4 + i][kk];
        a4[4 + i] = *(const float4*)&As[64 + ty * 4 + i][kk];
      }
      #pragma unroll
      for (int j = 0; j < 4; ++j) {
        float4 w0 = *(const float4*)&Ws[0][kk + j][tx * 4];
        float4 w1 = *(const float4*)&Ws[1][kk + j][tx * 4];
        float4 w2 = *(const float4*)&Ws[2][kk + j][tx * 4];
        float4 w3 = *(const float4*)&Ws[3][kk + j][tx * 4];
        const float* p0 = (const float*)&w0;
        const float* p1 = (const float*)&w1;
        const float* p2 = (const float*)&w2;
        const float* p3 = (const float*)&w3;
        #pragma unroll
        for (int i = 0; i < 8; ++i) {
          const float aa = ((const float*)&a4[i])[j];
          #pragma unroll
          for (int n = 0; n < 4; ++n) {
            acc[0][i][n] = fmaf(aa, p0[n], acc[0][i][n]);
            acc[1][i][n] = fmaf(aa, p1[n], acc[1][i][n]);
            acc[2][i][n] = fmaf(aa, p2[n], acc[2][i][n]);
            acc[3][i][n] = fmaf(aa, p3[n], acc[3][i][n]);
          }
        }
      }
    }
    __syncthreads();
  }

  float bQF[4], bQP[4], bKF[4], bKP[4];
  #pragma unroll
  for (int j = 0; j < 4; ++j) {
    bQF[j] = bqf[col0 + tx * 4 + j];
    bQP[j] = bqp[col0 + tx * 4 + j];
    bKF[j] = bkf[col0 + tx * 4 + j];
    bKP[j] = bkp[col0 + tx * 4 + j];
  }
  #pragma unroll
  for (int i = 0; i < 8; ++i) {
    const int r = (i < 4) ? (ty * 4 + i) : (64 + ty * 4 + i - 4);
    const int t = mb * 128 + r;
    const float tf = (float)t;
    // q
    {
      float w[4]; float ss = 0.f;
      #pragma unroll
      for (int j = 0; j < 4; ++j) {
        const float fv = acc[0][i][j] + bQF[j];
        const float pv = acc[1][i][j] + bQP[j];
        w[j] = sinf(fmaf(fv, tf, pv));
        ss += w[j] * w[j];
      }
      ss += __shfl_xor(ss, 1); ss += __shfl_xor(ss, 2);
      ss += __shfl_xor(ss, 4); ss += __shfl_xor(ss, 8);
      const float inv = 1.f / fmaxf(sqrtf(ss), 1e-12f);
      *(float4*)&QN[((size_t)(b * Tt + t) * Hh + h) * 64 + tx * 4] =
          make_float4(w[0] * inv, w[1] * inv, w[2] * inv, w[3] * inv);
    }
    // k
    {
      float w[4]; float ss = 0.f;
      #pragma unroll
      for (int j = 0; j < 4; ++j) {
        const float fv = acc[2][i][j] + bKF[j];
        const float pv = acc[3][i][j] + bKP[j];
        w[j] = sinf(fmaf(fv, tf, pv));
        ss += w[j] * w[j];
      }
      ss += __shfl_xor(ss, 1); ss += __shfl_xor(ss, 2);
      ss += __shfl_xor(ss, 4); ss += __shfl_xor(ss, 8);
      const float inv = 1.f / fmaxf(sqrtf(ss), 1e-12f);
      *(float4*)&KN[((size_t)(b * Tt + t) * Hh + h) * 64 + tx * 4] =
          make_float4(w[0] * inv, w[1] * inv, w[2] * inv, w[3] * inv);
    }
  }
}

// ---------------------------------------------------------------------------
// Kernel 2/7: tiled GEMM  C[M,1024] = A[M,1024] @ W[1024,1024] + bias (fp32)
// 128x128 tile, BK=32, 8x8 per thread, global->reg prefetch pipeline.
// ---------------------------------------------------------------------------
__global__ __launch_bounds__(256, 2) void gemm_kernel(
    const float* __restrict__ A, const float* __restrict__ W,
    const float* __restrict__ BIAS, float* __restrict__ OUT)
{
  __shared__ float As[128][36];
  __shared__ float Ws[32][132];

  const int tid = threadIdx.x;
  const int ty = tid >> 4, tx = tid & 15;
  const int m0 = blockIdx.x * 128, n0 = blockIdx.y * 128;

  float acc[8][8] = {{0.f}};

  const int ar = tid >> 3, ac4 = (tid & 7) * 4;
  const int wr = tid >> 5, wc4 = (tid & 31) * 4;

  float4 ra[4], rw[4];
  #pragma unroll
  for (int j = 0; j < 4; ++j) {
    ra[j] = *(const float4*)&A[(size_t)(m0 + ar + j * 32) * Dd + ac4];
    rw[j] = *(const float4*)&W[(size_t)(wr + j * 8) * Dd + n0 + wc4];
  }

  for (int k0 = 0; k0 < Dd; k0 += 32) {
    #pragma unroll
    for (int j = 0; j < 4; ++j) {
      *(float4*)&As[ar + j * 32][ac4] = ra[j];
      *(float4*)&Ws[wr + j * 8][wc4] = rw[j];
    }
    __syncthreads();

    if (k0 + 32 < Dd) {
      const int kn0 = k0 + 32;
      #pragma unroll
      for (int j = 0; j < 4; ++j) {
        ra[j] = *(const float4*)&A[(size_t)(m0 + ar + j * 32) * Dd + kn0 + ac4];
        rw[j] = *(const float4*)&W[(size_t)(kn0 + wr + j * 8) * Dd + n0 + wc4];
      }
    }

    #pragma unroll
    for (int kk = 0; kk < 32; kk += 4) {
      float4 a4[8], b4[2][4];
      #pragma unroll
      for (int i = 0; i < 4; ++i) {
        a4[i]     = *(const float4*)&As[ty * 4 + i][kk];
        a4[4 + i] = *(const float4*)&As[64 + ty * 4 + i][kk];
      }
      #pragma unroll
      for (int j = 0; j < 4; ++j) {
        b4[0][j] = *(const float4*)&Ws[kk + j][tx * 4];
        b4[1][j] = *(const float4*)&Ws[kk + j][64 + tx * 4];
      }
      #pragma unroll
      for (int j = 0; j < 4; ++j) {
        const float* b0 = (const float*)&b4[0][j];
        const float* b1 = (const float*)&b4[1][j];
        #pragma unroll
        for (int i = 0; i < 8; ++i) {
          const float aa = ((const float*)&a4[i])[j];
          #pragma unroll
          for (int n = 0; n < 4; ++n) {
            acc[i][n]     = fmaf(aa, b0[n], acc[i][n]);
            acc[i][4 + n] = fmaf(aa, b1[n], acc[i][4 + n]);
          }
        }
      }
    }
    __syncthreads();
  }

  float bn[8];
  #pragma unroll
  for (int j = 0; j < 4; ++j) {
    bn[j]     = BIAS[n0 + tx * 4 + j];
    bn[4 + j] = BIAS[n0 + 64 + tx * 4 + j];
  }
  #pragma unroll
  for (int i = 0; i < 8; ++i) {
    const int r = (i < 4) ? (ty * 4 + i) : (64 + ty * 4 + i - 4);
    const size_t m = (size_t)(m0 + r);
    *(float4*)&OUT[m * Dd + n0 + tx * 4] =
        make_float4(acc[i][0] + bn[0], acc[i][1] + bn[1],
                    acc[i][2] + bn[2], acc[i][3] + bn[3]);
    *(float4*)&OUT[m * Dd + n0 + 64 + tx * 4] =
        make_float4(acc[i][4] + bn[4], acc[i][5] + bn[5],
                    acc[i][6] + bn[6], acc[i][7] + bn[7]);
  }
}

// ---------------------------------------------------------------------------
// Kernel 3a: G_c[w][d] = sum_{s in chunk c} K[s][w] * V[s][d]   (64x64)
// ---------------------------------------------------------------------------
__global__ __launch_bounds__(256) void chunk_kv_kernel(
    const float* __restrict__ KN, const float* __restrict__ V,
    float* __restrict__ G)
{
  __shared__ float Ks[64][64];
  __shared__ float Vs[64][64];
  const int tid = threadIdx.x;
  const int c = blockIdx.x, h = blockIdx.y, b = blockIdx.z;
  const int s0 = c * 64;

  const int lr = tid >> 2;
  const int lc = (tid & 3) * 16;
  {
    const float* krow = &KN[((size_t)(b * Tt + s0 + lr) * Hh + h) * 64 + lc];
    const float* vrow = &V[((size_t)(b * Tt + s0 + lr)) * Dd + h * 64 + lc];
    #pragma unroll
    for (int i = 0; i < 4; ++i) {
      *(float4*)&Ks[lr][lc + i * 4] = *(const float4*)&krow[i * 4];
      *(float4*)&Vs[lr][lc + i * 4] = *(const float4*)&vrow[i * 4];
    }
  }
  __syncthreads();

  const int ty = tid >> 4, tx = tid & 15;
  float g[4][4] = {{0.f}};
  #pragma unroll 4
  for (int s = 0; s < 64; ++s) {
    float4 kv = *(const float4*)&Ks[s][ty * 4];
    float4 vv = *(const float4*)&Vs[s][tx * 4];
    const float* k_ = (const float*)&kv;
    const float* v_ = (const float*)&vv;
    #pragma unroll
    for (int i = 0; i < 4; ++i)
      #pragma unroll
      for (int j = 0; j < 4; ++j)
        g[i][j] = fmaf(k_[i], v_[j], g[i][j]);
  }

  float* Gp = G + (((size_t)(b * Hh + h) * NC + c) << 12);
  #pragma unroll
  for (int i = 0; i < 4; ++i)
    *(float4*)&Gp[(ty * 4 + i) * 64 + tx * 4] =
        make_float4(g[i][0], g[i][1], g[i][2], g[i][3]);
}

// ---------------------------------------------------------------------------
// Kernel 3b: in-place exclusive prefix over the NC chunk matrices per (b,h).
// ---------------------------------------------------------------------------
__global__ __launch_bounds__(256) void prefix_kernel(float* __restrict__ G)
{
  const int h = blockIdx.x, b = blockIdx.y;
  float* base = G + (((size_t)(b * Hh + h) * NC) << 12);
  const int off = threadIdx.x * 16;
  float4 a0 = make_float4(0.f, 0.f, 0.f, 0.f);
  float4 a1 = a0, a2 = a0, a3 = a0;
  for (int c = 0; c < NC; ++c) {
    float* p = base + ((size_t)c << 12) + off;
    float4 g0 = *(float4*)&p[0];
    float4 g1 = *(float4*)&p[4];
    float4 g2 = *(float4*)&p[8];
    float4 g3 = *(float4*)&p[12];
    *(float4*)&p[0]  = a0;
    *(float4*)&p[4]  = a1;
    *(float4*)&p[8]  = a2;
    *(float4*)&p[12] = a3;
    a0.x += g0.x; a0.y += g0.y; a0.z += g0.z; a0.w += g0.w;
    a1.x += g1.x; a1.y += g1.y; a1.z += g1.z; a1.w += g1.w;
    a2.x += g2.x; a2.y += g2.y; a2.z += g2.z; a2.w += g2.w;
    a3.x += g3.x; a3.y += g3.y; a3.z += g3.z; a3.w += g3.w;
  }
}

// ---------------------------------------------------------------------------
// Kernel 3c: O_c = (Q_c M_c + tril(Q_c K_c^T) V_c) * scale[h]/sqrt(t+1)
// ---------------------------------------------------------------------------
__global__ __launch_bounds__(256) void attn_chunk_kernel(
    const float* __restrict__ QN, const float* __restrict__ KN,
    const float* __restrict__ V, const float* __restrict__ M,
    const float* __restrict__ SCALE, float* __restrict__ ATT)
{
  __shared__ float Qt[64][68];
  __shared__ float Kt[64][68];
  __shared__ float SM[64][68];
  __shared__ float Vs[64][64];
  const int tid = threadIdx.x;
  const int c = blockIdx.x, h = blockIdx.y, b = blockIdx.z;
  const int t0 = c * 64;

  const int lr = tid >> 2;
  const int lc = (tid & 3) * 16;
  {
    const float* qrow = &QN[((size_t)(b * Tt + t0 + lr) * Hh + h) * 64 + lc];
    const float* krow = &KN[((size_t)(b * Tt + t0 + lr) * Hh + h) * 64 + lc];
    const float* vrow = &V[((size_t)(b * Tt + t0 + lr)) * Dd + h * 64 + lc];
    const float* mrow = &M[(((size_t)(b * Hh + h) * NC + c) << 12) + lr * 64 + lc];
    #pragma unroll
    for (int i = 0; i < 4; ++i) {
      float4 q = *(const float4*)&qrow[i * 4];
      float4 k = *(const float4*)&krow[i * 4];
      Qt[lc + i * 4 + 0][lr] = q.x; Qt[lc + i * 4 + 1][lr] = q.y;
      Qt[lc + i * 4 + 2][lr] = q.z; Qt[lc + i * 4 + 3][lr] = q.w;
      Kt[lc + i * 4 + 0][lr] = k.x; Kt[lc + i * 4 + 1][lr] = k.y;
      Kt[lc + i * 4 + 2][lr] = k.z; Kt[lc + i * 4 + 3][lr] = k.w;
      *(float4*)&Vs[lr][lc + i * 4] = *(const float4*)&vrow[i * 4];
      *(float4*)&SM[lr][lc + i * 4] = *(const float4*)&mrow[i * 4];
    }
  }
  __syncthreads();

  const int ty = tid >> 4, tx = tid & 15;
  float o[4][4]  = {{0.f}};
  float sc[4][4] = {{0.f}};

  #pragma unroll 4
  for (int w = 0; w < 64; ++w) {
    float4 qv = *(const float4*)&Qt[w][ty * 4];
    float4 mv = *(const float4*)&SM[w][tx * 4];
    float4 kv = *(const float4*)&Kt[w][tx * 4];
    const float* q_ = (const float*)&qv;
    const float* m_ = (const float*)&mv;
    const float* k_ = (const float*)&kv;
    #pragma unroll
    for (int i = 0; i < 4; ++i) {
      float qq = q_[i];
      #pragma unroll
      for (int j = 0; j < 4; ++j) {
        o[i][j]  = fmaf(qq, m_[j], o[i][j]);
        sc[i][j] = fmaf(qq, k_[j], sc[i][j]);
      }
    }
  }
  __syncthreads();

  #pragma unroll
  for (int i = 0; i < 4; ++i) {
    const int lt = ty * 4 + i;
    #pragma unroll
    for (int j = 0; j < 4; ++j) {
      const int ls = tx * 4 + j;
      SM[ls][lt] = (ls <= lt) ? sc[i][j] : 0.f;
    }
  }
  __syncthreads();

  #pragma unroll 4
  for (int s = 0; s < 64; ++s) {
    float4 sv = *(const float4*)&SM[s][ty * 4];
    float4 vv = *(const float4*)&Vs[s][tx * 4];
    const float* s_ = (const float*)&sv;
    const float* v_ = (const float*)&vv;
    #pragma unroll
    for (int i = 0; i < 4; ++i)
      #pragma unroll
      for (int j = 0; j < 4; ++j)
        o[i][j] = fmaf(s_[i], v_[j], o[i][j]);
  }

  const float sch = SCALE[h];
  #pragma unroll
  for (int i = 0; i < 4; ++i) {
    const int t = t0 + ty * 4 + i;
    const float fac = sch / sqrtf((float)(t + 1));
    *(float4*)&ATT[((size_t)(b * Tt + t)) * Dd + h * 64 + tx * 4] =
        make_float4(o[i][0] * fac, o[i][1] * fac, o[i][2] * fac, o[i][3] * fac);
  }
}

// ---------------------------------------------------------------------------
extern "C" void kernel_launch(void* const* d_in, const int* in_sizes, int n_in,
                              void* d_out, int out_size, void* d_ws, size_t ws_size,
                              hipStream_t stream) {
  const float* x   = (const float*)d_in[0];
  const float* Wqf = (const float*)d_in[1];
  const float* bqf = (const float*)d_in[2];
  const float* Wkf = (const float*)d_in[3];
  const float* bkf = (const float*)d_in[4];
  const float* Wqp = (const float*)d_in[5];
  const float* bqp = (const float*)d_in[6];
  const float* Wkp = (const float*)d_in[7];
  const float* bkp = (const float*)d_in[8];
  const float* Wv  = (const float*)d_in[9];
  const float* bv  = (const float*)d_in[10];
  const float* Wo  = (const float*)d_in[11];
  const float* bo  = (const float*)d_in[12];
  const float* scale = (const float*)d_in[13];

  const size_t NTOK = (size_t)Bb * Tt * Dd;  // 4,194,304
  float* qn   = (float*)d_ws;
  float* kn   = qn + NTOK;
  float* vbuf = kn + NTOK;
  float* G    = vbuf + NTOK;
  float* att  = qn;   // ALIAS (safe: see header comment)

  proj_wave4_kernel<<<dim3(Tt / 128, Hh, Bb), 256, 0, stream>>>(
      x, Wqf, bqf, Wqp, bqp, Wkf, bkf, Wkp, bkp, qn, kn);

  dim3 gg((Bb * Tt) / 128, Dd / 128);  // (32, 8)
  gemm_kernel<<<gg, 256, 0, stream>>>(x, Wv, bv, vbuf);

  chunk_kv_kernel<<<dim3(NC, Hh, Bb), 256, 0, stream>>>(kn, vbuf, G);
  prefix_kernel<<<dim3(Hh, Bb), 256, 0, stream>>>(G);
  attn_chunk_kernel<<<dim3(NC, Hh, Bb), 256, 0, stream>>>(qn, kn, vbuf, G, scale, att);

  gemm_kernel<<<gg, 256, 0, stream>>>(att, Wo, bo, (float*)d_out);
}

// Round 7
// 457.642 us; speedup vs baseline: 2.1496x; 2.1496x over previous
//
#include <hip/hip_runtime.h>

// PureWaveAttention B=2,T=2048,D=1024,H=16,NW=64,HD=64 — fp32 I/O, but all
// GEMMs run on MFMA via 2-term fp16 split: a = hi + lo/2048 (lo stored
// pre-scaled x2048 to stay fp16-normal), C = hh(hi,hi) + mx(hi,lo + lo,hi)/2048.
// Representation error 2^-22 rel < fp32 fma-chain noise -> fp32-equivalent.
// Pipeline:
//  0) wsplit: W{qf,qp,kf,kp,v,o} fp32[k][n] -> Whi/Wlo fp16[n][k] (transposed)
//  1) proj: qn/kn = normalize(sin((x@Wf+bf)*t + (x@Wp+bp))) -> fp16 [B,T,H*64]
//  2) vgemm: v = x@Wv+bv -> fp32, stored in d_out (consumed before out-gemm)
//  3) chunk_kv -> G; prefix -> M; attn_chunk -> att split fp16 (aliases qn/kn)
//  4) outgemm: d_out = att@Wo+bo (A from pre-split att halves)
// ws (56 MB): Wsplit 24 | qnh 8 | knh 8 | G 16.  atthi aliases qnh, attlo knh
// (block (c,h) is sole reader of its slab; reads staged to LDS before writes).

#define Bb 2
#define Tt 2048
#define Dd 1024
#define Hh 16
#define NC 32

typedef _Float16 half_t;
typedef _Float16 half8 __attribute__((ext_vector_type(8)));
typedef _Float16 half4h __attribute__((ext_vector_type(4)));
typedef float float4v __attribute__((ext_vector_type(4)));

#define MFMA16(a, b, c) __builtin_amdgcn_mfma_f32_16x16x32_f16((a), (b), (c), 0, 0, 0)

// ---------------------------------------------------------------------------
// Kernel 0: split+transpose weights: W[k][n] fp32 -> hi[n][k], lo[n][k] fp16.
// Per matrix: hi at m*2097152 halves, lo at +1048576.
// ---------------------------------------------------------------------------
__global__ __launch_bounds__(256) void wsplit_kernel(
    const float* __restrict__ W0, const float* __restrict__ W1,
    const float* __restrict__ W2, const float* __restrict__ W3,
    const float* __restrict__ W4, const float* __restrict__ W5,
    half_t* __restrict__ WSP)
{
  __shared__ float Ld[64][68];
  const int tid = threadIdx.x;
  const int m = blockIdx.z;
  const float* W = (m == 0) ? W0 : (m == 1) ? W1 : (m == 2) ? W2
                 : (m == 3) ? W3 : (m == 4) ? W4 : W5;
  const int k0 = blockIdx.x * 64, n0 = blockIdx.y * 64;
  const int r = tid >> 2, c4 = (tid & 3) * 16;
  #pragma unroll
  for (int i = 0; i < 4; ++i)
    *(float4*)&Ld[r][c4 + i * 4] =
        *(const float4*)&W[(size_t)(k0 + r) * Dd + n0 + c4 + i * 4];
  __syncthreads();
  half_t* hi = WSP + (size_t)m * 2097152;
  half_t* lo = hi + 1048576;
  const int n = tid >> 2, kc = (tid & 3) * 16;
  half8 hv0, hv1, lv0, lv1;
  #pragma unroll
  for (int i = 0; i < 8; ++i) {
    float v0 = Ld[kc + i][n];
    half_t h0 = (half_t)v0;
    hv0[i] = h0; lv0[i] = (half_t)((v0 - (float)h0) * 2048.f);
    float v1 = Ld[kc + 8 + i][n];
    half_t h1 = (half_t)v1;
    hv1[i] = h1; lv1[i] = (half_t)((v1 - (float)h1) * 2048.f);
  }
  *(half8*)&hi[(size_t)(n0 + n) * Dd + k0 + kc]     = hv0;
  *(half8*)&hi[(size_t)(n0 + n) * Dd + k0 + kc + 8] = hv1;
  *(half8*)&lo[(size_t)(n0 + n) * Dd + k0 + kc]     = lv0;
  *(half8*)&lo[(size_t)(n0 + n) * Dd + k0 + kc + 8] = lv1;
}

// ---------------------------------------------------------------------------
// Kernel 1: proj. Block = (64 t-rows, head h, pair p: 0=q,1=k). N=128 =
// F cols (0..63) | P cols (64..127). Wave w -> rows 16w, 8 MFMA tiles.
// Epilogue: f,p in same lane -> sin(f*t+p), L2-normalize -> fp16 out.
// ---------------------------------------------------------------------------
__global__ __launch_bounds__(256, 3) void proj_kernel(
    const float* __restrict__ X, const half_t* __restrict__ WSP,
    const float* __restrict__ bqf, const float* __restrict__ bqp,
    const float* __restrict__ bkf, const float* __restrict__ bkp,
    half_t* __restrict__ QNH, half_t* __restrict__ KNH)
{
  __shared__ half_t Ahi[64][40], Alo[64][40];
  __shared__ half_t Bhi[128][40], Blo[128][40];
  const int tid = threadIdx.x;
  const int mb = blockIdx.x, h = blockIdx.y;
  const int b = blockIdx.z >> 1, p = blockIdx.z & 1;
  const int t0 = mb * 64, row0 = b * Tt + t0, col0 = h * 64;
  const half_t* WF = WSP + (size_t)(2 * p) * 2097152;      // hi; lo at +1048576
  const half_t* WP = WSP + (size_t)(2 * p + 1) * 2097152;
  const float* BF = p ? bkf : bqf;
  const float* BP = p ? bkp : bqp;
  half_t* OUTH = p ? KNH : QNH;

  float4v hh[8], mx[8];
  #pragma unroll
  for (int i = 0; i < 8; ++i) { hh[i] = (float4v){0.f,0.f,0.f,0.f}; mx[i] = hh[i]; }

  const int lane = tid & 63, wave = tid >> 6;
  const int lm = lane & 15, lq = lane >> 4;
  const int wrow = wave * 16;
  const int sbn = tid >> 2, sbk = (tid & 3) * 8;

  for (int k0 = 0; k0 < Dd; k0 += 32) {
    #pragma unroll
    for (int j = 0; j < 2; ++j) {
      const int idx = tid + j * 256;
      const int r = idx >> 3, kc = (idx & 7) * 4;
      float4 a = *(const float4*)&X[(size_t)(row0 + r) * Dd + k0 + kc];
      const float av[4] = {a.x, a.y, a.z, a.w};
      half4h hv, lv;
      #pragma unroll
      for (int i = 0; i < 4; ++i) {
        half_t hx = (half_t)av[i];
        hv[i] = hx; lv[i] = (half_t)((av[i] - (float)hx) * 2048.f);
      }
      *(half4h*)&Ahi[r][kc] = hv;
      *(half4h*)&Alo[r][kc] = lv;
    }
    *(half8*)&Bhi[sbn][sbk]      = *(const half8*)&WF[(size_t)(col0 + sbn) * Dd + k0 + sbk];
    *(half8*)&Blo[sbn][sbk]      = *(const half8*)&WF[1048576 + (size_t)(col0 + sbn) * Dd + k0 + sbk];
    *(half8*)&Bhi[64 + sbn][sbk] = *(const half8*)&WP[(size_t)(col0 + sbn) * Dd + k0 + sbk];
    *(half8*)&Blo[64 + sbn][sbk] = *(const half8*)&WP[1048576 + (size_t)(col0 + sbn) * Dd + k0 + sbk];
    __syncthreads();
    half8 ahi = *(const half8*)&Ahi[wrow + lm][lq * 8];
    half8 alo = *(const half8*)&Alo[wrow + lm][lq * 8];
    #pragma unroll
    for (int tn = 0; tn < 8; ++tn) {
      half8 bhi = *(const half8*)&Bhi[tn * 16 + lm][lq * 8];
      half8 blo = *(const half8*)&Blo[tn * 16 + lm][lq * 8];
      hh[tn] = MFMA16(ahi, bhi, hh[tn]);
      mx[tn] = MFMA16(ahi, blo, mx[tn]);
      mx[tn] = MFMA16(alo, bhi, mx[tn]);
    }
    __syncthreads();
  }

  float fb[4], pb[4];
  #pragma unroll
  for (int j = 0; j < 4; ++j) {
    fb[j] = BF[col0 + j * 16 + lm];
    pb[j] = BP[col0 + j * 16 + lm];
  }
  #pragma unroll
  for (int r = 0; r < 4; ++r) {
    const int t = t0 + wrow + lq * 4 + r;
    const float tf = (float)t;
    float w[4]; float ss = 0.f;
    #pragma unroll
    for (int j = 0; j < 4; ++j) {
      float f  = hh[j][r]     + mx[j][r]     * (1.f / 2048.f) + fb[j];
      float pp = hh[4 + j][r] + mx[4 + j][r] * (1.f / 2048.f) + pb[j];
      w[j] = sinf(fmaf(f, tf, pp));
      ss += w[j] * w[j];
    }
    ss += __shfl_xor(ss, 1); ss += __shfl_xor(ss, 2);
    ss += __shfl_xor(ss, 4); ss += __shfl_xor(ss, 8);
    const float inv = 1.f / fmaxf(sqrtf(ss), 1e-12f);
    #pragma unroll
    for (int j = 0; j < 4; ++j)
      OUTH[(size_t)(b * Tt + t) * Dd + col0 + j * 16 + lm] = (half_t)(w[j] * inv);
  }
}

// ---------------------------------------------------------------------------
// Kernel 2/4: GEMM C[M,1024] = A@W + bias, split-fp16 MFMA. M-tile 64,
// N-tile 128. A from fp32 (split on fly) or pre-split halves.
// ---------------------------------------------------------------------------
template<bool AF32>
__global__ __launch_bounds__(256, 3) void gemm_split_kernel(
    const float* __restrict__ A32,
    const half_t* __restrict__ AHI, const half_t* __restrict__ ALO,
    const half_t* __restrict__ WHI,   // lo at +1048576
    const float* __restrict__ BIAS, float* __restrict__ OUT)
{
  __shared__ half_t Ahi[64][40], Alo[64][40];
  __shared__ half_t Bhi[128][40], Blo[128][40];
  const int tid = threadIdx.x;
  const int m0 = blockIdx.x * 64, n0 = blockIdx.y * 128;

  float4v hh[8], mx[8];
  #pragma unroll
  for (int i = 0; i < 8; ++i) { hh[i] = (float4v){0.f,0.f,0.f,0.f}; mx[i] = hh[i]; }

  const int lane = tid & 63, wave = tid >> 6;
  const int lm = lane & 15, lq = lane >> 4;
  const int wrow = wave * 16;
  const int sar = tid >> 2, sak = (tid & 3) * 8;

  for (int k0 = 0; k0 < Dd; k0 += 32) {
    if constexpr (AF32) {
      #pragma unroll
      for (int j = 0; j < 2; ++j) {
        const int idx = tid + j * 256;
        const int r = idx >> 3, kc = (idx & 7) * 4;
        float4 a = *(const float4*)&A32[(size_t)(m0 + r) * Dd + k0 + kc];
        const float av[4] = {a.x, a.y, a.z, a.w};
        half4h hv, lv;
        #pragma unroll
        for (int i = 0; i < 4; ++i) {
          half_t hx = (half_t)av[i];
          hv[i] = hx; lv[i] = (half_t)((av[i] - (float)hx) * 2048.f);
        }
        *(half4h*)&Ahi[r][kc] = hv;
        *(half4h*)&Alo[r][kc] = lv;
      }
    } else {
      *(half8*)&Ahi[sar][sak] = *(const half8*)&AHI[(size_t)(m0 + sar) * Dd + k0 + sak];
      *(half8*)&Alo[sar][sak] = *(const half8*)&ALO[(size_t)(m0 + sar) * Dd + k0 + sak];
    }
    #pragma unroll
    for (int j = 0; j < 2; ++j) {
      const int idx = tid + j * 256;
      const int n = idx >> 2, kp = (idx & 3) * 8;
      *(half8*)&Bhi[n][kp] = *(const half8*)&WHI[(size_t)(n0 + n) * Dd + k0 + kp];
      *(half8*)&Blo[n][kp] = *(const half8*)&WHI[1048576 + (size_t)(n0 + n) * Dd + k0 + kp];
    }
    __syncthreads();
    half8 ahi = *(const half8*)&Ahi[wrow + lm][lq * 8];
    half8 alo = *(const half8*)&Alo[wrow + lm][lq * 8];
    #pragma unroll
    for (int tn = 0; tn < 8; ++tn) {
      half8 bhi = *(const half8*)&Bhi[tn * 16 + lm][lq * 8];
      half8 blo = *(const half8*)&Blo[tn * 16 + lm][lq * 8];
      hh[tn] = MFMA16(ahi, bhi, hh[tn]);
      mx[tn] = MFMA16(ahi, blo, mx[tn]);
      mx[tn] = MFMA16(alo, bhi, mx[tn]);
    }
    __syncthreads();
  }

  #pragma unroll
  for (int tn = 0; tn < 8; ++tn) {
    const float bn = BIAS[n0 + tn * 16 + lm];
    #pragma unroll
    for (int r = 0; r < 4; ++r) {
      const int row = m0 + wrow + lq * 4 + r;
      OUT[(size_t)row * Dd + n0 + tn * 16 + lm] =
          hh[tn][r] + mx[tn][r] * (1.f / 2048.f) + bn;
    }
  }
}

// ---------------------------------------------------------------------------
// Kernel 3a: G_c[w][d] = sum_{s in c} K[s][w]*V[s][d]. K from fp16, V fp32.
// ---------------------------------------------------------------------------
__global__ __launch_bounds__(256) void chunk_kv_kernel(
    const half_t* __restrict__ KNH, const float* __restrict__ V,
    float* __restrict__ G)
{
  __shared__ float Ks[64][64];
  __shared__ float Vs[64][64];
  const int tid = threadIdx.x;
  const int c = blockIdx.x, h = blockIdx.y, b = blockIdx.z;
  const int s0 = c * 64;
  const int lr = tid >> 2, lc = (tid & 3) * 16;
  {
    const half_t* krow = &KNH[(size_t)(b * Tt + s0 + lr) * Dd + h * 64 + lc];
    half8 ka = *(const half8*)&krow[0];
    half8 kb = *(const half8*)&krow[8];
    #pragma unroll
    for (int i = 0; i < 8; ++i) {
      Ks[lr][lc + i] = (float)ka[i];
      Ks[lr][lc + 8 + i] = (float)kb[i];
    }
    const float* vrow = &V[(size_t)(b * Tt + s0 + lr) * Dd + h * 64 + lc];
    #pragma unroll
    for (int i = 0; i < 4; ++i)
      *(float4*)&Vs[lr][lc + i * 4] = *(const float4*)&vrow[i * 4];
  }
  __syncthreads();

  const int ty = tid >> 4, tx = tid & 15;
  float g[4][4] = {{0.f}};
  #pragma unroll 4
  for (int s = 0; s < 64; ++s) {
    float4 kv = *(const float4*)&Ks[s][ty * 4];
    float4 vv = *(const float4*)&Vs[s][tx * 4];
    const float* k_ = (const float*)&kv;
    const float* v_ = (const float*)&vv;
    #pragma unroll
    for (int i = 0; i < 4; ++i)
      #pragma unroll
      for (int j = 0; j < 4; ++j)
        g[i][j] = fmaf(k_[i], v_[j], g[i][j]);
  }
  float* Gp = G + (((size_t)(b * Hh + h) * NC + c) << 12);
  #pragma unroll
  for (int i = 0; i < 4; ++i)
    *(float4*)&Gp[(ty * 4 + i) * 64 + tx * 4] =
        make_float4(g[i][0], g[i][1], g[i][2], g[i][3]);
}

// ---------------------------------------------------------------------------
// Kernel 3b: in-place exclusive prefix over NC chunk matrices per (b,h).
// ---------------------------------------------------------------------------
__global__ __launch_bounds__(256) void prefix_kernel(float* __restrict__ G)
{
  const int h = blockIdx.x, b = blockIdx.y;
  float* base = G + (((size_t)(b * Hh + h) * NC) << 12);
  const int off = threadIdx.x * 16;
  float4 a0 = make_float4(0.f, 0.f, 0.f, 0.f);
  float4 a1 = a0, a2 = a0, a3 = a0;
  for (int c = 0; c < NC; ++c) {
    float* p = base + ((size_t)c << 12) + off;
    float4 g0 = *(float4*)&p[0];
    float4 g1 = *(float4*)&p[4];
    float4 g2 = *(float4*)&p[8];
    float4 g3 = *(float4*)&p[12];
    *(float4*)&p[0] = a0; *(float4*)&p[4] = a1;
    *(float4*)&p[8] = a2; *(float4*)&p[12] = a3;
    a0.x += g0.x; a0.y += g0.y; a0.z += g0.z; a0.w += g0.w;
    a1.x += g1.x; a1.y += g1.y; a1.z += g1.z; a1.w += g1.w;
    a2.x += g2.x; a2.y += g2.y; a2.z += g2.z; a2.w += g2.w;
    a3.x += g3.x; a3.y += g3.y; a3.z += g3.z; a3.w += g3.w;
  }
}

// ---------------------------------------------------------------------------
// Kernel 3c: O_c = (Q_c M_c + tril(Q_c K_c^T) V_c) * scale/sqrt(t+1).
// Q,K from fp16; out split to fp16 hi/lo (lo x2048), aliasing qnh/knh.
// ---------------------------------------------------------------------------
__global__ __launch_bounds__(256) void attn_chunk_kernel(
    const half_t* __restrict__ QNH, const half_t* __restrict__ KNH,
    const float* __restrict__ V, const float* __restrict__ M,
    const float* __restrict__ SCALE,
    half_t* __restrict__ ATTHI, half_t* __restrict__ ATTLO)
{
  __shared__ float Qt[64][68];
  __shared__ float Kt[64][68];
  __shared__ float SM[64][68];
  __shared__ float Vs[64][64];
  const int tid = threadIdx.x;
  const int c = blockIdx.x, h = blockIdx.y, b = blockIdx.z;
  const int t0 = c * 64;
  const int lr = tid >> 2, lc = (tid & 3) * 16;
  {
    const half_t* qrow = &QNH[(size_t)(b * Tt + t0 + lr) * Dd + h * 64 + lc];
    const half_t* krow = &KNH[(size_t)(b * Tt + t0 + lr) * Dd + h * 64 + lc];
    half8 qa = *(const half8*)&qrow[0];
    half8 qb = *(const half8*)&qrow[8];
    half8 ka = *(const half8*)&krow[0];
    half8 kb = *(const half8*)&krow[8];
    #pragma unroll
    for (int i = 0; i < 8; ++i) {
      Qt[lc + i][lr] = (float)qa[i];     Qt[lc + 8 + i][lr] = (float)qb[i];
      Kt[lc + i][lr] = (float)ka[i];     Kt[lc + 8 + i][lr] = (float)kb[i];
    }
    const float* vrow = &V[(size_t)(b * Tt + t0 + lr) * Dd + h * 64 + lc];
    const float* mrow = &M[(((size_t)(b * Hh + h) * NC + c) << 12) + lr * 64 + lc];
    #pragma unroll
    for (int i = 0; i < 4; ++i) {
      *(float4*)&Vs[lr][lc + i * 4] = *(const float4*)&vrow[i * 4];
      *(float4*)&SM[lr][lc + i * 4] = *(const float4*)&mrow[i * 4];
    }
  }
  __syncthreads();

  const int ty = tid >> 4, tx = tid & 15;
  float o[4][4] = {{0.f}};
  float sc[4][4] = {{0.f}};

  #pragma unroll 4
  for (int w = 0; w < 64; ++w) {
    float4 qv = *(const float4*)&Qt[w][ty * 4];
    float4 mv = *(const float4*)&SM[w][tx * 4];
    float4 kv = *(const float4*)&Kt[w][tx * 4];
    const float* q_ = (const float*)&qv;
    const float* m_ = (const float*)&mv;
    const float* k_ = (const float*)&kv;
    #pragma unroll
    for (int i = 0; i < 4; ++i) {
      float qq = q_[i];
      #pragma unroll
      for (int j = 0; j < 4; ++j) {
        o[i][j]  = fmaf(qq, m_[j], o[i][j]);
        sc[i][j] = fmaf(qq, k_[j], sc[i][j]);
      }
    }
  }
  __syncthreads();

  #pragma unroll
  for (int i = 0; i < 4; ++i) {
    const int lt = ty * 4 + i;
    #pragma unroll
    for (int j = 0; j < 4; ++j) {
      const int ls = tx * 4 + j;
      SM[ls][lt] = (ls <= lt) ? sc[i][j] : 0.f;
    }
  }
  __syncthreads();

  #pragma unroll 4
  for (int s = 0; s < 64; ++s) {
    float4 sv = *(const float4*)&SM[s][ty * 4];
    float4 vv = *(const float4*)&Vs[s][tx * 4];
    const float* s_ = (const float*)&sv;
    const float* v_ = (const float*)&vv;
    #pragma unroll
    for (int i = 0; i < 4; ++i)
      #pragma unroll
      for (int j = 0; j < 4; ++j)
        o[i][j] = fmaf(s_[i], v_[j], o[i][j]);
  }

  const float sch = SCALE[h];
  #pragma unroll
  for (int i = 0; i < 4; ++i) {
    const int t = t0 + ty * 4 + i;
    const float fac = sch / sqrtf((float)(t + 1));
    half4h hv, lv;
    #pragma unroll
    for (int j = 0; j < 4; ++j) {
      float v = o[i][j] * fac;
      half_t hx = (half_t)v;
      hv[j] = hx; lv[j] = (half_t)((v - (float)hx) * 2048.f);
    }
    *(half4h*)&ATTHI[(size_t)(b * Tt + t) * Dd + h * 64 + tx * 4] = hv;
    *(half4h*)&ATTLO[(size_t)(b * Tt + t) * Dd + h * 64 + tx * 4] = lv;
  }
}

// ---------------------------------------------------------------------------
extern "C" void kernel_launch(void* const* d_in, const int* in_sizes, int n_in,
                              void* d_out, int out_size, void* d_ws, size_t ws_size,
                              hipStream_t stream) {
  const float* x   = (const float*)d_in[0];
  const float* Wqf = (const float*)d_in[1];
  const float* bqf = (const float*)d_in[2];
  const float* Wkf = (const float*)d_in[3];
  const float* bkf = (const float*)d_in[4];
  const float* Wqp = (const float*)d_in[5];
  const float* bqp = (const float*)d_in[6];
  const float* Wkp = (const float*)d_in[7];
  const float* bkp = (const float*)d_in[8];
  const float* Wv  = (const float*)d_in[9];
  const float* bv  = (const float*)d_in[10];
  const float* Wo  = (const float*)d_in[11];
  const float* bo  = (const float*)d_in[12];
  const float* scale = (const float*)d_in[13];

  // ws layout (56 MB): Wsplit 24 MB | qnh 8 MB | knh 8 MB | G 16 MB
  half_t* WSP = (half_t*)d_ws;                 // 6 mats x (hi 1M + lo 1M) halves
  half_t* qnh = WSP + 12582912;                // 4,194,304 halves
  half_t* knh = qnh + 4194304;
  float*  G   = (float*)(knh + 4194304);
  float*  vbuf = (float*)d_out;                // v lives in d_out, consumed
                                               // before the final out-gemm

  // mat order in WSP: 0=qf 1=qp 2=kf 3=kp 4=v 5=o
  wsplit_kernel<<<dim3(16, 16, 6), 256, 0, stream>>>(Wqf, Wqp, Wkf, Wkp, Wv, Wo, WSP);

  proj_kernel<<<dim3(Tt / 64, Hh, Bb * 2), 256, 0, stream>>>(
      x, WSP, bqf, bqp, bkf, bkp, qnh, knh);

  gemm_split_kernel<true><<<dim3((Bb * Tt) / 64, Dd / 128), 256, 0, stream>>>(
      x, nullptr, nullptr, WSP + (size_t)4 * 2097152, bv, vbuf);

  chunk_kv_kernel<<<dim3(NC, Hh, Bb), 256, 0, stream>>>(knh, vbuf, G);
  prefix_kernel<<<dim3(Hh, Bb), 256, 0, stream>>>(G);
  attn_chunk_kernel<<<dim3(NC, Hh, Bb), 256, 0, stream>>>(
      qnh, knh, vbuf, G, scale, qnh /*atthi*/, knh /*attlo*/);

  gemm_split_kernel<false><<<dim3((Bb * Tt) / 64, Dd / 128), 256, 0, stream>>>(
      nullptr, qnh, knh, WSP + (size_t)5 * 2097152, bo, (float*)d_out);
}